// Round 1
// 767.558 us; speedup vs baseline: 1.0188x; 1.0188x over previous
//
#include <hip/hip_runtime.h>

#define B_ 16
#define H_ 768
#define N_ 2048
#define SCALE 0.03608439182435161f  // 1/sqrt(768)

typedef unsigned short u16;
typedef unsigned int u32;
typedef __attribute__((ext_vector_type(8))) short short8;   // 8 bf16
typedef __attribute__((ext_vector_type(4))) float float4v;  // MFMA acc

__device__ __forceinline__ u16 f2bf(float f) {
  u32 u = __float_as_uint(f);
  u32 r = (u + 0x7FFFu + ((u >> 16) & 1u)) >> 16;  // RNE
  return (u16)r;
}
__device__ __forceinline__ float bf2f(u16 h) { return __uint_as_float(((u32)h) << 16); }
__device__ __forceinline__ u32 pk2(float a, float b) {
  return (u32)f2bf(a) | ((u32)f2bf(b) << 16);
}

// async global->LDS, 16B per lane. LDS dest must be wave-uniform base + lane*16.
__device__ __forceinline__ void dma16(const void* g, void* l) {
  __builtin_amdgcn_global_load_lds(
      (const __attribute__((address_space(1))) void*)g,
      (__attribute__((address_space(3))) void*)l, 16, 0, 0);
}

// ---------------------------------------------------------------------------
// K0: transpose+convert.  which=0: q -> qT bf16 [B][N][H]
//                         which=1: (k+pe) -> keffT bf16 [B][N][H]
__global__ __launch_bounds__(256) void kt_transpose(
    const float* __restrict__ q, const float* __restrict__ k,
    const float* __restrict__ pe, u16* __restrict__ qT, u16* __restrict__ keffT) {
  __shared__ float tile[64][65];  // +1 pad kills bank conflicts
  const int t = threadIdx.x;
  const int b = blockIdx.z & 15;
  const int which = blockIdx.z >> 4;
  const float* src = which ? k : q;
  u16* dst = which ? keffT : qT;
  const size_t inb = (size_t)b * H_ * N_;
  const size_t outb = (size_t)b * N_ * H_;
  const int n0 = blockIdx.x * 64;
  const int h0 = blockIdx.y * 64;
  const int col = t & 63;  // n offset, coalesced reads
  const int r0 = t >> 6;
#pragma unroll
  for (int i = 0; i < 16; ++i) {
    const int row = r0 + i * 4;  // h offset
    const size_t idx = inb + (size_t)(h0 + row) * N_ + (n0 + col);
    float v = src[idx];
    if (which) v += pe[idx];
    tile[row][col] = v;
  }
  __syncthreads();
  const int w = t & 31;   // h pair
  const int r1 = t >> 5;  // n sub-row
#pragma unroll
  for (int i = 0; i < 8; ++i) {
    const int row = r1 + i * 8;  // n offset
    const u32 u = pk2(tile[2 * w][row], tile[2 * w + 1][row]);
    *(u32*)(dst + outb + (size_t)(n0 + row) * H_ + (h0 + 2 * w)) = u;
  }
}

// ---------------------------------------------------------------------------
// K0b: v fp32 [B][H][N] -> bf16 [B][H][N] (no transpose; hoists the convert
// that k2 used to do per-h-tile in its K-loop staging).
__global__ __launch_bounds__(256) void kv_convert(
    const float* __restrict__ v, u16* __restrict__ vB) {
  const size_t i = ((size_t)blockIdx.x * 256 + threadIdx.x) * 8;
  float4 a = *(const float4*)&v[i];
  float4 b = *(const float4*)&v[i + 4];
  uint4 o;
  o.x = pk2(a.x, a.y);
  o.y = pk2(a.z, a.w);
  o.z = pk2(b.x, b.y);
  o.w = pk2(b.z, b.w);
  *(uint4*)&vB[i] = o;
}

// ---------------------------------------------------------------------------
// K1: S[n][m] = qT[n][:] . keffT[m][:]   (K = 768), raw bf16 scores out.
// m97-style: 128x128 tile, 4 waves each 64x64, BK=32, 16B DMA staging.
__global__ __launch_bounds__(256) void k1_qk_gemm(
    const u16* __restrict__ qT, const u16* __restrict__ keffT, u16* __restrict__ S) {
  __shared__ __align__(16) u16 ldsA[128 * 32];
  __shared__ __align__(16) u16 ldsB[128 * 32];
  __shared__ __align__(16) float ldsC[32 * 132];  // chunked epilogue, padded
  const int t = threadIdx.x;
  const int lane = t & 63;
  const int wv = t >> 6;
  const int wr = wv >> 1, wc = wv & 1;
  const int b = blockIdx.z;
  const int m0 = blockIdx.x * 128;
  const int n0 = blockIdx.y * 128;
  const u16* Ab = qT + (size_t)b * N_ * H_ + (size_t)n0 * H_;    // rows n, stride H
  const u16* Bb = keffT + (size_t)b * N_ * H_ + (size_t)m0 * H_; // rows m, stride H
  float4v acc[4][4] = {};
  const int fr = lane & 15;
  const int fk = (lane >> 4) * 8;
  for (int k0 = 0; k0 < H_; k0 += 32) {
    __syncthreads();
#pragma unroll
    for (int r = 0; r < 2; ++r) {
      const int c = r * 256 + t;
      const int row = c >> 2;
      const int co = (c & 3) * 8;
      dma16(Ab + (size_t)row * H_ + (k0 + co), &ldsA[c * 8]);
      dma16(Bb + (size_t)row * H_ + (k0 + co), &ldsB[c * 8]);
    }
    __syncthreads();
    short8 af[4], bfv[4];
#pragma unroll
    for (int i = 0; i < 4; ++i)
      af[i] = *(const short8*)&ldsA[(wr * 64 + i * 16 + fr) * 32 + fk];
#pragma unroll
    for (int j = 0; j < 4; ++j)
      bfv[j] = *(const short8*)&ldsB[(wc * 64 + j * 16 + fr) * 32 + fk];
#pragma unroll
    for (int i = 0; i < 4; ++i)
#pragma unroll
      for (int j = 0; j < 4; ++j)
        acc[i][j] = __builtin_amdgcn_mfma_f32_16x16x32_bf16(af[i], bfv[j], acc[i][j], 0, 0, 0);
  }
  // epilogue: acc -> ldsC (32-row chunks) -> coalesced bf16 stores
  const int cr = lane >> 4;
  const int cc = lane & 15;
  const size_t Sb = (size_t)b * N_ * N_;
  const int orow = t >> 3;
  const int ocol = (t & 7) * 16;
  for (int chunk = 0; chunk < 4; ++chunk) {
    __syncthreads();
    if (wr == (chunk >> 1)) {
#pragma unroll
      for (int ii = 0; ii < 2; ++ii) {
        const int i = (chunk & 1) * 2 + ii;
#pragma unroll
        for (int j = 0; j < 4; ++j)
#pragma unroll
          for (int r = 0; r < 4; ++r)
            ldsC[(ii * 16 + cr * 4 + r) * 132 + (wc * 64 + j * 16 + cc)] = acc[i][j][r];
      }
    }
    __syncthreads();
    const float* srcp = &ldsC[orow * 132 + ocol];
    float4 fA = *(const float4*)&srcp[0];
    float4 fB = *(const float4*)&srcp[4];
    float4 fC = *(const float4*)&srcp[8];
    float4 fD = *(const float4*)&srcp[12];
    uint4 o0, o1;
    o0.x = pk2(fA.x, fA.y); o0.y = pk2(fA.z, fA.w);
    o0.z = pk2(fB.x, fB.y); o0.w = pk2(fB.z, fB.w);
    o1.x = pk2(fC.x, fC.y); o1.y = pk2(fC.z, fC.w);
    o1.z = pk2(fD.x, fD.y); o1.w = pk2(fD.z, fD.w);
    u16* dst = S + Sb + (size_t)(n0 + chunk * 32 + orow) * N_ + (m0 + ocol);
    *(uint4*)dst = o0;
    *(uint4*)(dst + 8) = o1;
  }
}

// ---------------------------------------------------------------------------
// K1b: row-wise softmax over m, in place.  One wave per row, 32 elems/lane.
__global__ __launch_bounds__(256) void k1b_softmax(u16* __restrict__ S) {
  const int t = threadIdx.x;
  const int lane = t & 63;
  const int wv = t >> 6;
  const size_t row = (size_t)blockIdx.x * 4 + wv;  // b*N + n
  u16* base = S + row * N_;
  float x[32];
#pragma unroll
  for (int c = 0; c < 4; ++c) {
    uint4 u = *(const uint4*)&base[c * 512 + lane * 8];
    const u32 uu[4] = {u.x, u.y, u.z, u.w};
#pragma unroll
    for (int e = 0; e < 4; ++e) {
      x[c * 8 + e * 2] = bf2f((u16)(uu[e] & 0xFFFFu));
      x[c * 8 + e * 2 + 1] = bf2f((u16)(uu[e] >> 16));
    }
  }
  float mx = -1e30f;
#pragma unroll
  for (int e = 0; e < 32; ++e) mx = fmaxf(mx, x[e]);
#pragma unroll
  for (int off = 32; off > 0; off >>= 1) mx = fmaxf(mx, __shfl_xor(mx, off));
  float sum = 0.f;
#pragma unroll
  for (int e = 0; e < 32; ++e) {
    x[e] = __expf((x[e] - mx) * SCALE);
    sum += x[e];
  }
#pragma unroll
  for (int off = 32; off > 0; off >>= 1) sum += __shfl_xor(sum, off);
  const float rinv = 1.0f / sum;
#pragma unroll
  for (int c = 0; c < 4; ++c) {
    uint4 o;
    o.x = pk2(x[c * 8 + 0] * rinv, x[c * 8 + 1] * rinv);
    o.y = pk2(x[c * 8 + 2] * rinv, x[c * 8 + 3] * rinv);
    o.z = pk2(x[c * 8 + 4] * rinv, x[c * 8 + 5] * rinv);
    o.w = pk2(x[c * 8 + 6] * rinv, x[c * 8 + 7] * rinv);
    *(uint4*)&base[c * 512 + lane * 8] = o;
  }
}

// ---------------------------------------------------------------------------
// K2: out[h][n] = sum_m vB[h][m] * P[n][m]   (K = 2048).
// Both operands bf16, both DMA-staged (v pre-converted by kv_convert).
__global__ __launch_bounds__(256) void k2_pv_gemm(
    const u16* __restrict__ vB, const u16* __restrict__ P, float* __restrict__ out) {
  __shared__ __align__(16) u16 ldsA[128 * 32];
  __shared__ __align__(16) u16 ldsB[128 * 32];
  const int t = threadIdx.x;
  const int lane = t & 63;
  const int wv = t >> 6;
  const int wr = wv >> 1, wc = wv & 1;
  const int b = blockIdx.z;
  const int n0 = blockIdx.x * 128;
  const int h0 = blockIdx.y * 128;
  const u16* Ab = vB + (size_t)b * H_ * N_ + (size_t)h0 * N_;  // rows h, stride N
  const u16* Bb = P + (size_t)b * N_ * N_ + (size_t)n0 * N_;   // rows n, stride N
  float4v acc[4][4] = {};
  const int fr = lane & 15;
  const int fk = (lane >> 4) * 8;
  for (int k0 = 0; k0 < N_; k0 += 32) {
    __syncthreads();
#pragma unroll
    for (int r = 0; r < 2; ++r) {
      const int c = r * 256 + t;
      const int row = c >> 2;
      const int co = (c & 3) * 8;
      dma16(Ab + (size_t)row * N_ + (k0 + co), &ldsA[c * 8]);
      dma16(Bb + (size_t)row * N_ + (k0 + co), &ldsB[c * 8]);
    }
    __syncthreads();
    short8 af[4], bfv[4];
#pragma unroll
    for (int i = 0; i < 4; ++i)
      af[i] = *(const short8*)&ldsA[(wr * 64 + i * 16 + fr) * 32 + fk];
#pragma unroll
    for (int j = 0; j < 4; ++j)
      bfv[j] = *(const short8*)&ldsB[(wc * 64 + j * 16 + fr) * 32 + fk];
#pragma unroll
    for (int i = 0; i < 4; ++i)
#pragma unroll
      for (int j = 0; j < 4; ++j)
        acc[i][j] = __builtin_amdgcn_mfma_f32_16x16x32_bf16(af[i], bfv[j], acc[i][j], 0, 0, 0);
  }
  const int cr = lane >> 4, cc = lane & 15;
  const size_t ob = (size_t)b * H_ * N_;
#pragma unroll
  for (int i = 0; i < 4; ++i) {
    const int hh = h0 + wr * 64 + i * 16 + cr * 4;
#pragma unroll
    for (int j = 0; j < 4; ++j) {
      const int nn = n0 + wc * 64 + j * 16 + cc;
#pragma unroll
      for (int r = 0; r < 4; ++r)
        out[ob + (size_t)(hh + r) * N_ + nn] = acc[i][j][r];
    }
  }
}

// ---------------------------------------------------------------------------
extern "C" void kernel_launch(void* const* d_in, const int* in_sizes, int n_in,
                              void* d_out, int out_size, void* d_ws, size_t ws_size,
                              hipStream_t stream) {
  const float* q = (const float*)d_in[0];
  const float* k = (const float*)d_in[1];
  const float* v = (const float*)d_in[2];
  const float* pe = (const float*)d_in[3];
  float* out = (float*)d_out;
  char* ws = (char*)d_ws;
  // ws layout: qT (48 MiB) | keffT (48 MiB) | S/P (128 MiB)  => 224 MiB total
  // vB (48 MiB) REUSES the qT region: qT is dead after k1, stream is serial.
  u16* qT = (u16*)ws;
  u16* keffT = (u16*)(ws + 50331648);
  u16* S = (u16*)(ws + 100663296);
  u16* vB = (u16*)ws;

  hipLaunchKernelGGL(kt_transpose, dim3(32, 12, 32), dim3(256), 0, stream, q, k, pe, qT, keffT);
  hipLaunchKernelGGL(k1_qk_gemm, dim3(16, 16, 16), dim3(256), 0, stream, qT, keffT, S);
  // qT now dead -> overwrite with bf16 v
  hipLaunchKernelGGL(kv_convert, dim3(12288), dim3(256), 0, stream, v, vB);
  hipLaunchKernelGGL(k1b_softmax, dim3(8192), dim3(256), 0, stream, S);
  hipLaunchKernelGGL(k2_pv_gemm, dim3(16, 6, 16), dim3(256), 0, stream, vB, S, out);
}

// Round 2
// 727.993 us; speedup vs baseline: 1.0741x; 1.0543x over previous
//
#include <hip/hip_runtime.h>

#define B_ 16
#define H_ 768
#define N_ 2048
#define SCALE 0.03608439182435161f  // 1/sqrt(768)

typedef unsigned short u16;
typedef unsigned int u32;
typedef __attribute__((ext_vector_type(8))) short short8;   // 8 bf16
typedef __attribute__((ext_vector_type(4))) float float4v;  // MFMA acc

__device__ __forceinline__ u16 f2bf(float f) {
  u32 u = __float_as_uint(f);
  u32 r = (u + 0x7FFFu + ((u >> 16) & 1u)) >> 16;  // RNE
  return (u16)r;
}
__device__ __forceinline__ float bf2f(u16 h) { return __uint_as_float(((u32)h) << 16); }
__device__ __forceinline__ u32 pk2(float a, float b) {
  return (u32)f2bf(a) | ((u32)f2bf(b) << 16);
}

// async global->LDS, 16B per lane. LDS dest must be wave-uniform base + lane*16.
__device__ __forceinline__ void dma16(const void* g, void* l) {
  __builtin_amdgcn_global_load_lds(
      (const __attribute__((address_space(1))) void*)g,
      (__attribute__((address_space(3))) void*)l, 16, 0, 0);
}

// ---------------------------------------------------------------------------
// K0: transpose+convert.  which=0: q -> qT bf16 [B][N][H]
//                         which=1: (k+pe) -> keffT bf16 [B][N][H]
// float4 reads (16B/lane), uint2 writes (8B/lane).
__global__ __launch_bounds__(256) void kt_transpose(
    const float* __restrict__ q, const float* __restrict__ k,
    const float* __restrict__ pe, u16* __restrict__ qT, u16* __restrict__ keffT) {
  __shared__ float tile[64][65];  // +1 pad kills bank conflicts
  const int t = threadIdx.x;
  const int b = blockIdx.z & 15;
  const int which = blockIdx.z >> 4;
  const float* src = which ? k : q;
  u16* dst = which ? keffT : qT;
  const size_t inb = (size_t)b * H_ * N_;
  const size_t outb = (size_t)b * N_ * H_;
  const int n0 = blockIdx.x * 64;
  const int h0 = blockIdx.y * 64;
  const int col4 = (t & 15) * 4;  // n offset, float4 coalesced
  const int r0 = t >> 4;          // 0..15
#pragma unroll
  for (int i = 0; i < 4; ++i) {
    const int row = r0 + i * 16;  // h offset
    const size_t idx = inb + (size_t)(h0 + row) * N_ + (n0 + col4);
    float4 v = *(const float4*)&src[idx];
    if (which) {
      float4 p = *(const float4*)&pe[idx];
      v.x += p.x; v.y += p.y; v.z += p.z; v.w += p.w;
    }
    tile[row][col4 + 0] = v.x;
    tile[row][col4 + 1] = v.y;
    tile[row][col4 + 2] = v.z;
    tile[row][col4 + 3] = v.w;
  }
  __syncthreads();
  const int w2 = t & 15;  // h quad
  const int r1 = t >> 4;  // n sub-row
#pragma unroll
  for (int i = 0; i < 4; ++i) {
    const int row = r1 + i * 16;  // n offset
    uint2 u;
    u.x = pk2(tile[4 * w2 + 0][row], tile[4 * w2 + 1][row]);
    u.y = pk2(tile[4 * w2 + 2][row], tile[4 * w2 + 3][row]);
    *(uint2*)(dst + outb + (size_t)(n0 + row) * H_ + (h0 + 4 * w2)) = u;
  }
}

// ---------------------------------------------------------------------------
// K0b: v fp32 [B][H][N] -> bf16 [B][H][N]
__global__ __launch_bounds__(256) void kv_convert(
    const float* __restrict__ v, u16* __restrict__ vB) {
  const size_t i = ((size_t)blockIdx.x * 256 + threadIdx.x) * 8;
  float4 a = *(const float4*)&v[i];
  float4 b = *(const float4*)&v[i + 4];
  uint4 o;
  o.x = pk2(a.x, a.y);
  o.y = pk2(a.z, a.w);
  o.z = pk2(b.x, b.y);
  o.w = pk2(b.z, b.w);
  *(uint4*)&vB[i] = o;
}

// ---------------------------------------------------------------------------
// K1: S[n][m] = qT[n][:] . keffT[m][:]   (K = 768), raw bf16 scores out.
// 2-phase double-buffered 256x256 tile, BK=64, 8 waves (2 n-half x 4 m-quad).
// STAGE(next) issued BEFORE compute(cur); one __syncthreads per K-tile does
// the vmcnt drain -> HBM latency hides under ~2500 cyc of MFMA (T3 minimum).
__global__ __launch_bounds__(512, 2) void k1_qk_gemm(
    const u16* __restrict__ qT, const u16* __restrict__ keffT, u16* __restrict__ S) {
  __shared__ __align__(16) u16 lds[2][2][256 * 64];  // [dbuf][A/B][row*64+k] = 128 KiB
  const int t = threadIdx.x;
  const int lane = t & 63;
  const int wv = t >> 6;
  const int wm = wv >> 2;  // n-half 0/1   (A rows, output rows)
  const int wn = wv & 3;   // m-quad 0..3  (B rows, output cols)
  const int b = blockIdx.z;
  const int m0 = blockIdx.x * 256;
  const int n0 = blockIdx.y * 256;
  const u16* Ab = qT + (size_t)b * N_ * H_ + (size_t)n0 * H_;    // rows n, stride H
  const u16* Bb = keffT + (size_t)b * N_ * H_ + (size_t)m0 * H_; // rows m, stride H
  float4v acc[8][4] = {};
  const int fr = lane & 15;
  const int fk = (lane >> 4) * 8;

#define STAGE_K1(buf, kt)                                                     \
  {                                                                           \
    const int kbase = (kt)*64;                                                \
    _Pragma("unroll") for (int r = 0; r < 4; ++r) {                           \
      const int c = r * 512 + t;                                              \
      const int row = c >> 3;                                                 \
      const int k8 = (c & 7) * 8;                                             \
      dma16(Ab + (size_t)row * H_ + (kbase + k8), &lds[buf][0][c * 8]);       \
      dma16(Bb + (size_t)row * H_ + (kbase + k8), &lds[buf][1][c * 8]);       \
    }                                                                         \
  }

  STAGE_K1(0, 0);
  __syncthreads();  // drain prologue
  const int NT = H_ / 64;  // 12
  for (int kt = 0; kt < NT; ++kt) {
    const int buf = kt & 1;
    if (kt + 1 < NT) STAGE_K1(buf ^ 1, kt + 1);  // prefetch next tile (flight = full phase)
    const u16* LA = &lds[buf][0][0];
    const u16* LB = &lds[buf][1][0];
#pragma unroll
    for (int ks = 0; ks < 2; ++ks) {
      short8 af[8], bfv[4];
#pragma unroll
      for (int i = 0; i < 8; ++i)
        af[i] = *(const short8*)&LA[(wm * 128 + i * 16 + fr) * 64 + ks * 32 + fk];
#pragma unroll
      for (int j = 0; j < 4; ++j)
        bfv[j] = *(const short8*)&LB[(wn * 64 + j * 16 + fr) * 64 + ks * 32 + fk];
#pragma unroll
      for (int i = 0; i < 8; ++i)
#pragma unroll
        for (int j = 0; j < 4; ++j)
          acc[i][j] = __builtin_amdgcn_mfma_f32_16x16x32_bf16(af[i], bfv[j], acc[i][j], 0, 0, 0);
    }
    __syncthreads();  // vmcnt(0)+lgkm drain + barrier: next tile landed, all reads done
  }
#undef STAGE_K1

  // epilogue: 4 chunks of 64 rows via LDS f32 [64][264] (reuses staging LDS)
  float* ldsC = (float*)&lds[0][0][0];  // 64*264*4 = 67.6 KiB < 128 KiB
  const int cr = lane >> 4, cc = lane & 15;
  const size_t Sb = (size_t)b * N_ * N_;
  const int orow = t >> 3;        // 0..63
  const int ocol = (t & 7) * 32;  // 0..224
  for (int ch = 0; ch < 4; ++ch) {
    if (wm == (ch >> 1)) {
#pragma unroll
      for (int ii = 0; ii < 4; ++ii) {
        const int i = (ch & 1) * 4 + ii;
#pragma unroll
        for (int j = 0; j < 4; ++j)
#pragma unroll
          for (int r = 0; r < 4; ++r)
            ldsC[(ii * 16 + cr * 4 + r) * 264 + (wn * 64 + j * 16 + cc)] = acc[i][j][r];
      }
    }
    __syncthreads();
    const float* srcp = &ldsC[orow * 264 + ocol];
    uint4 o4[4];
#pragma unroll
    for (int e = 0; e < 4; ++e) {
      float4 f0 = *(const float4*)&srcp[e * 8];
      float4 f1 = *(const float4*)&srcp[e * 8 + 4];
      o4[e].x = pk2(f0.x, f0.y);
      o4[e].y = pk2(f0.z, f0.w);
      o4[e].z = pk2(f1.x, f1.y);
      o4[e].w = pk2(f1.z, f1.w);
    }
    u16* dst = S + Sb + (size_t)(n0 + ch * 64 + orow) * N_ + (m0 + ocol);
#pragma unroll
    for (int e = 0; e < 4; ++e) *(uint4*)(dst + e * 8) = o4[e];
    __syncthreads();
  }
}

// ---------------------------------------------------------------------------
// K1b: row-wise softmax over m, in place.  One wave per row, 32 elems/lane.
__global__ __launch_bounds__(256) void k1b_softmax(u16* __restrict__ S) {
  const int t = threadIdx.x;
  const int lane = t & 63;
  const int wv = t >> 6;
  const size_t row = (size_t)blockIdx.x * 4 + wv;  // b*N + n
  u16* base = S + row * N_;
  float x[32];
#pragma unroll
  for (int c = 0; c < 4; ++c) {
    uint4 u = *(const uint4*)&base[c * 512 + lane * 8];
    const u32 uu[4] = {u.x, u.y, u.z, u.w};
#pragma unroll
    for (int e = 0; e < 4; ++e) {
      x[c * 8 + e * 2] = bf2f((u16)(uu[e] & 0xFFFFu));
      x[c * 8 + e * 2 + 1] = bf2f((u16)(uu[e] >> 16));
    }
  }
  float mx = -1e30f;
#pragma unroll
  for (int e = 0; e < 32; ++e) mx = fmaxf(mx, x[e]);
#pragma unroll
  for (int off = 32; off > 0; off >>= 1) mx = fmaxf(mx, __shfl_xor(mx, off));
  float sum = 0.f;
#pragma unroll
  for (int e = 0; e < 32; ++e) {
    x[e] = __expf((x[e] - mx) * SCALE);
    sum += x[e];
  }
#pragma unroll
  for (int off = 32; off > 0; off >>= 1) sum += __shfl_xor(sum, off);
  const float rinv = 1.0f / sum;
#pragma unroll
  for (int c = 0; c < 4; ++c) {
    uint4 o;
    o.x = pk2(x[c * 8 + 0] * rinv, x[c * 8 + 1] * rinv);
    o.y = pk2(x[c * 8 + 2] * rinv, x[c * 8 + 3] * rinv);
    o.z = pk2(x[c * 8 + 4] * rinv, x[c * 8 + 5] * rinv);
    o.w = pk2(x[c * 8 + 6] * rinv, x[c * 8 + 7] * rinv);
    *(uint4*)&base[c * 512 + lane * 8] = o;
  }
}

// ---------------------------------------------------------------------------
// K2: out[h][n] = sum_m vB[h][m] * P[n][m]   (K = 2048).
// Both operands bf16, both DMA-staged (v pre-converted by kv_convert).
__global__ __launch_bounds__(256) void k2_pv_gemm(
    const u16* __restrict__ vB, const u16* __restrict__ P, float* __restrict__ out) {
  __shared__ __align__(16) u16 ldsA[128 * 32];
  __shared__ __align__(16) u16 ldsB[128 * 32];
  const int t = threadIdx.x;
  const int lane = t & 63;
  const int wv = t >> 6;
  const int wr = wv >> 1, wc = wv & 1;
  const int b = blockIdx.z;
  const int n0 = blockIdx.x * 128;
  const int h0 = blockIdx.y * 128;
  const u16* Ab = vB + (size_t)b * H_ * N_ + (size_t)h0 * N_;  // rows h, stride N
  const u16* Bb = P + (size_t)b * N_ * N_ + (size_t)n0 * N_;   // rows n, stride N
  float4v acc[4][4] = {};
  const int fr = lane & 15;
  const int fk = (lane >> 4) * 8;
  for (int k0 = 0; k0 < N_; k0 += 32) {
    __syncthreads();
#pragma unroll
    for (int r = 0; r < 2; ++r) {
      const int c = r * 256 + t;
      const int row = c >> 2;
      const int co = (c & 3) * 8;
      dma16(Ab + (size_t)row * N_ + (k0 + co), &ldsA[c * 8]);
      dma16(Bb + (size_t)row * N_ + (k0 + co), &ldsB[c * 8]);
    }
    __syncthreads();
    short8 af[4], bfv[4];
#pragma unroll
    for (int i = 0; i < 4; ++i)
      af[i] = *(const short8*)&ldsA[(wr * 64 + i * 16 + fr) * 32 + fk];
#pragma unroll
    for (int j = 0; j < 4; ++j)
      bfv[j] = *(const short8*)&ldsB[(wc * 64 + j * 16 + fr) * 32 + fk];
#pragma unroll
    for (int i = 0; i < 4; ++i)
#pragma unroll
      for (int j = 0; j < 4; ++j)
        acc[i][j] = __builtin_amdgcn_mfma_f32_16x16x32_bf16(af[i], bfv[j], acc[i][j], 0, 0, 0);
  }
  const int cr = lane >> 4, cc = lane & 15;
  const size_t ob = (size_t)b * H_ * N_;
#pragma unroll
  for (int i = 0; i < 4; ++i) {
    const int hh = h0 + wr * 64 + i * 16 + cr * 4;
#pragma unroll
    for (int j = 0; j < 4; ++j) {
      const int nn = n0 + wc * 64 + j * 16 + cc;
#pragma unroll
      for (int r = 0; r < 4; ++r)
        out[ob + (size_t)(hh + r) * N_ + nn] = acc[i][j][r];
    }
  }
}

// ---------------------------------------------------------------------------
extern "C" void kernel_launch(void* const* d_in, const int* in_sizes, int n_in,
                              void* d_out, int out_size, void* d_ws, size_t ws_size,
                              hipStream_t stream) {
  const float* q = (const float*)d_in[0];
  const float* k = (const float*)d_in[1];
  const float* v = (const float*)d_in[2];
  const float* pe = (const float*)d_in[3];
  float* out = (float*)d_out;
  char* ws = (char*)d_ws;
  // ws layout: qT (48 MiB) | keffT (48 MiB) | S/P (128 MiB)  => 224 MiB total
  // vB (48 MiB) REUSES the qT region: qT is dead after k1, stream is serial.
  u16* qT = (u16*)ws;
  u16* keffT = (u16*)(ws + 50331648);
  u16* S = (u16*)(ws + 100663296);
  u16* vB = (u16*)ws;

  hipLaunchKernelGGL(kt_transpose, dim3(32, 12, 32), dim3(256), 0, stream, q, k, pe, qT, keffT);
  hipLaunchKernelGGL(k1_qk_gemm, dim3(8, 8, 16), dim3(512), 0, stream, qT, keffT, S);
  // qT now dead -> overwrite with bf16 v
  hipLaunchKernelGGL(kv_convert, dim3(12288), dim3(256), 0, stream, v, vB);
  hipLaunchKernelGGL(k1b_softmax, dim3(8192), dim3(256), 0, stream, S);
  hipLaunchKernelGGL(k2_pv_gemm, dim3(16, 6, 16), dim3(256), 0, stream, vB, S, out);
}

// Round 3
// 673.416 us; speedup vs baseline: 1.1612x; 1.0810x over previous
//
#include <hip/hip_runtime.h>

#define B_ 16
#define H_ 768
#define N_ 2048
#define SCALE 0.03608439182435161f  // 1/sqrt(768)

typedef unsigned short u16;
typedef unsigned int u32;
typedef __attribute__((ext_vector_type(8))) short short8;   // 8 bf16
typedef __attribute__((ext_vector_type(4))) float float4v;  // MFMA acc

__device__ __forceinline__ float bf2f(u16 h) { return __uint_as_float(((u32)h) << 16); }
// packed f32x2 -> bf16x2, RNE via hardware cvt (T12 recipe; no builtin on gfx950)
__device__ __forceinline__ u32 pk2(float a, float b) {
  u32 r;
  asm("v_cvt_pk_bf16_f32 %0, %1, %2" : "=v"(r) : "v"(a), "v"(b));
  return r;
}

// async global->LDS, 16B per lane. LDS dest must be wave-uniform base + lane*16.
__device__ __forceinline__ void dma16(const void* g, void* l) {
  __builtin_amdgcn_global_load_lds(
      (const __attribute__((address_space(1))) void*)g,
      (__attribute__((address_space(3))) void*)l, 16, 0, 0);
}

// ---------------------------------------------------------------------------
// K0: transpose+convert.  which=0: q -> qT bf16 [B][N][H]
//                         which=1: (k+pe) -> keffT bf16 [B][N][H]
__global__ __launch_bounds__(256) void kt_transpose(
    const float* __restrict__ q, const float* __restrict__ k,
    const float* __restrict__ pe, u16* __restrict__ qT, u16* __restrict__ keffT) {
  __shared__ float tile[64][65];  // +1 pad kills bank conflicts
  const int t = threadIdx.x;
  const int b = blockIdx.z & 15;
  const int which = blockIdx.z >> 4;
  const float* src = which ? k : q;
  u16* dst = which ? keffT : qT;
  const size_t inb = (size_t)b * H_ * N_;
  const size_t outb = (size_t)b * N_ * H_;
  const int n0 = blockIdx.x * 64;
  const int h0 = blockIdx.y * 64;
  const int col4 = (t & 15) * 4;  // n offset, float4 coalesced
  const int r0 = t >> 4;          // 0..15
#pragma unroll
  for (int i = 0; i < 4; ++i) {
    const int row = r0 + i * 16;  // h offset
    const size_t idx = inb + (size_t)(h0 + row) * N_ + (n0 + col4);
    float4 v = *(const float4*)&src[idx];
    if (which) {
      float4 p = *(const float4*)&pe[idx];
      v.x += p.x; v.y += p.y; v.z += p.z; v.w += p.w;
    }
    tile[row][col4 + 0] = v.x;
    tile[row][col4 + 1] = v.y;
    tile[row][col4 + 2] = v.z;
    tile[row][col4 + 3] = v.w;
  }
  __syncthreads();
  const int w2 = t & 15;  // h quad
  const int r1 = t >> 4;  // n sub-row
#pragma unroll
  for (int i = 0; i < 4; ++i) {
    const int row = r1 + i * 16;  // n offset
    uint2 u;
    u.x = pk2(tile[4 * w2 + 0][row], tile[4 * w2 + 1][row]);
    u.y = pk2(tile[4 * w2 + 2][row], tile[4 * w2 + 3][row]);
    *(uint2*)(dst + outb + (size_t)(n0 + row) * H_ + (h0 + 4 * w2)) = u;
  }
}

// ---------------------------------------------------------------------------
// K0b: v fp32 [B][H][N] -> bf16 [B][H][N]
__global__ __launch_bounds__(256) void kv_convert(
    const float* __restrict__ v, u16* __restrict__ vB) {
  const size_t i = ((size_t)blockIdx.x * 256 + threadIdx.x) * 8;
  float4 a = *(const float4*)&v[i];
  float4 b = *(const float4*)&v[i + 4];
  uint4 o;
  o.x = pk2(a.x, a.y);
  o.y = pk2(a.z, a.w);
  o.z = pk2(b.x, b.y);
  o.w = pk2(b.z, b.w);
  *(uint4*)&vB[i] = o;
}

// ---------------------------------------------------------------------------
// K1: S[n][m] = qT[n][:] . keffT[m][:]   (K = 768), raw bf16 scores out.
// 256x256 tile, BK=32, 8 waves (2 n-half x 4 m-quad).
// T4: 3-buffer LDS ring, depth-2 prefetch, counted vmcnt (never 0 in steady
//     state) + raw s_barrier; lgkmcnt(0) before barrier protects WAR.
// T2: 16B-slot XOR swizzle (slot ^ ((row>>1)&3)) applied on the GLOBAL source
//     (gload_lds lands linear) and identically on the ds_read address ->
//     2 lanes/bank (free, m136).
#define K1_LOADS 4
__global__ __launch_bounds__(512, 2) void k1_qk_gemm(
    const u16* __restrict__ qT, const u16* __restrict__ keffT, u16* __restrict__ S) {
  __shared__ __align__(16) u16 lds[3][2][256 * 32];  // [ring][A/B], 96 KiB
  const int t = threadIdx.x;
  const int lane = t & 63;
  const int wv = t >> 6;
  const int wm = wv >> 2;  // n-half 0/1   (output rows)
  const int wn = wv & 3;   // m-quad 0..3  (output cols)
  // T1 bijective XCD swizzle: nwg = 8*8*16 = 1024, chunk = 128
  int lid = blockIdx.x + (blockIdx.y << 3) + (blockIdx.z << 6);
  lid = (lid & 7) * 128 + (lid >> 3);
  const int bx = lid & 7;
  const int by = (lid >> 3) & 7;
  const int bz = lid >> 6;
  const int m0 = bx * 256;
  const int n0 = by * 256;
  const u16* Ab = qT + (size_t)bz * N_ * H_ + (size_t)n0 * H_;    // rows n, stride H
  const u16* Bb = keffT + (size_t)bz * N_ * H_ + (size_t)m0 * H_; // rows m, stride H
  float4v acc[8][4] = {};
  const int fr = lane & 15;
  const int g = lane >> 4;

#define STAGE1(buf, kt_)                                                      \
  {                                                                           \
    const int kb = (kt_) * 32;                                                \
    _Pragma("unroll") for (int r = 0; r < 2; ++r) {                           \
      const int c = r * 512 + t;                                              \
      const int row = c >> 2;                                                 \
      const int sl = c & 3;                                                   \
      const int gcol = kb + ((sl ^ ((row >> 1) & 3)) << 3);                   \
      dma16(Ab + (size_t)row * H_ + gcol, &lds[buf][0][c * 8]);               \
      dma16(Bb + (size_t)row * H_ + gcol, &lds[buf][1][c * 8]);               \
    }                                                                         \
  }

  STAGE1(0, 0);
  STAGE1(1, 1);
  asm volatile("s_waitcnt vmcnt(%0)" ::"i"(K1_LOADS) : "memory");
  __builtin_amdgcn_s_barrier();
  const int NT = H_ / 32;  // 24
  for (int kt_ = 0; kt_ < NT; ++kt_) {
    const int b = kt_ % 3;
    const bool pf = (kt_ + 2 < NT);
    if (pf) STAGE1((kt_ + 2) % 3, kt_ + 2);
    const u16* LA = &lds[b][0][0];
    const u16* LB = &lds[b][1][0];
    short8 bfv[4], af[8];
#pragma unroll
    for (int j = 0; j < 4; ++j) {
      const int row = wn * 64 + j * 16 + fr;
      bfv[j] = *(const short8*)&LB[row * 32 + ((g ^ ((row >> 1) & 3)) << 3)];
    }
#pragma unroll
    for (int i = 0; i < 8; ++i) {
      const int row = wm * 128 + i * 16 + fr;
      af[i] = *(const short8*)&LA[row * 32 + ((g ^ ((row >> 1) & 3)) << 3)];
    }
#pragma unroll
    for (int i = 0; i < 8; ++i)
#pragma unroll
      for (int j = 0; j < 4; ++j)
        acc[i][j] = __builtin_amdgcn_mfma_f32_16x16x32_bf16(af[i], bfv[j], acc[i][j], 0, 0, 0);
    // boundary: next tile's loads retired (counted), my LDS reads COMPLETE
    // (WAR vs the stage that will overwrite this buffer), then barrier.
    if (pf)
      asm volatile("s_waitcnt vmcnt(%0) lgkmcnt(0)" ::"i"(K1_LOADS) : "memory");
    else
      asm volatile("s_waitcnt vmcnt(0) lgkmcnt(0)" ::: "memory");
    __builtin_amdgcn_s_barrier();
  }
#undef STAGE1

  // epilogue: 4 chunks of 64 rows via LDS f32 [64][264] (reuses staging LDS)
  float* ldsC = (float*)&lds[0][0][0];  // 67.6 KiB < 96 KiB
  const int cr = lane >> 4, cc = lane & 15;
  const size_t Sb = (size_t)bz * N_ * N_;
  const int orow = t >> 3;        // 0..63
  const int ocol = (t & 7) * 32;  // 0..224
  for (int ch = 0; ch < 4; ++ch) {
    if (wm == (ch >> 1)) {
#pragma unroll
      for (int ii = 0; ii < 4; ++ii) {
        const int i = (ch & 1) * 4 + ii;
#pragma unroll
        for (int j = 0; j < 4; ++j)
#pragma unroll
          for (int r = 0; r < 4; ++r)
            ldsC[(ii * 16 + cr * 4 + r) * 264 + (wn * 64 + j * 16 + cc)] = acc[i][j][r];
      }
    }
    __syncthreads();
    const float* srcp = &ldsC[orow * 264 + ocol];
    uint4 o4[4];
#pragma unroll
    for (int e = 0; e < 4; ++e) {
      float4 f0 = *(const float4*)&srcp[e * 8];
      float4 f1 = *(const float4*)&srcp[e * 8 + 4];
      o4[e].x = pk2(f0.x, f0.y);
      o4[e].y = pk2(f0.z, f0.w);
      o4[e].z = pk2(f1.x, f1.y);
      o4[e].w = pk2(f1.z, f1.w);
    }
    u16* dst = S + Sb + (size_t)(n0 + ch * 64 + orow) * N_ + (m0 + ocol);
#pragma unroll
    for (int e = 0; e < 4; ++e) *(uint4*)(dst + e * 8) = o4[e];
    __syncthreads();
  }
}

// ---------------------------------------------------------------------------
// K1b: row-wise softmax over m, in place.  One wave per row, 32 elems/lane.
__global__ __launch_bounds__(256) void k1b_softmax(u16* __restrict__ S) {
  const int t = threadIdx.x;
  const int lane = t & 63;
  const int wv = t >> 6;
  const size_t row = (size_t)blockIdx.x * 4 + wv;  // b*N + n
  u16* base = S + row * N_;
  float x[32];
#pragma unroll
  for (int c = 0; c < 4; ++c) {
    uint4 u = *(const uint4*)&base[c * 512 + lane * 8];
    const u32 uu[4] = {u.x, u.y, u.z, u.w};
#pragma unroll
    for (int e = 0; e < 4; ++e) {
      x[c * 8 + e * 2] = bf2f((u16)(uu[e] & 0xFFFFu));
      x[c * 8 + e * 2 + 1] = bf2f((u16)(uu[e] >> 16));
    }
  }
  float mx = -1e30f;
#pragma unroll
  for (int e = 0; e < 32; ++e) mx = fmaxf(mx, x[e]);
#pragma unroll
  for (int off = 32; off > 0; off >>= 1) mx = fmaxf(mx, __shfl_xor(mx, off));
  float sum = 0.f;
#pragma unroll
  for (int e = 0; e < 32; ++e) {
    x[e] = __expf((x[e] - mx) * SCALE);
    sum += x[e];
  }
#pragma unroll
  for (int off = 32; off > 0; off >>= 1) sum += __shfl_xor(sum, off);
  const float rinv = 1.0f / sum;
#pragma unroll
  for (int c = 0; c < 4; ++c) {
    uint4 o;
    o.x = pk2(x[c * 8 + 0] * rinv, x[c * 8 + 1] * rinv);
    o.y = pk2(x[c * 8 + 2] * rinv, x[c * 8 + 3] * rinv);
    o.z = pk2(x[c * 8 + 4] * rinv, x[c * 8 + 5] * rinv);
    o.w = pk2(x[c * 8 + 6] * rinv, x[c * 8 + 7] * rinv);
    *(uint4*)&base[c * 512 + lane * 8] = o;
  }
}

// ---------------------------------------------------------------------------
// K2: out[h][n] = sum_m vB[h][m] * P[n][m]   (K = 2048).
// 128(h) x 256(n) tile, BK=32, 8 waves (2 h-half x 4 n-quad), same T4 ring +
// T2 slot swizzle as k1.  Grid 8*6*16 = 768 = 3 exact CU rounds.
#define K2_LOADS 3
__global__ __launch_bounds__(512, 2) void k2_pv_gemm(
    const u16* __restrict__ vB, const u16* __restrict__ P, float* __restrict__ out) {
  __shared__ __align__(16) u16 lds[3][12288];  // A:128x32 @0, B:256x32 @4096; 72 KiB
  const int t = threadIdx.x;
  const int lane = t & 63;
  const int wv = t >> 6;
  const int wm = wv >> 2;  // h half (64 rows)
  const int wn = wv & 3;   // n quad (64 cols)
  // T1 bijective XCD swizzle: nwg = 8*6*16 = 768, chunk = 96
  int lid = blockIdx.x + 8 * (blockIdx.y + 6 * blockIdx.z);
  lid = (lid & 7) * 96 + (lid >> 3);
  const int bx = lid & 7;
  const int rem = lid >> 3;
  const int by = rem % 6;
  const int bz = rem / 6;
  const int n0 = bx * 256;
  const int h0 = by * 128;
  const u16* Ab = vB + (size_t)bz * H_ * N_ + (size_t)h0 * N_;  // rows h, stride N
  const u16* Bb = P + (size_t)bz * N_ * N_ + (size_t)n0 * N_;   // rows n, stride N
  float4v acc[4][4] = {};
  const int fr = lane & 15;
  const int g = lane >> 4;

#define STAGE2(buf, kt_)                                                      \
  {                                                                           \
    const int kb = (kt_) * 32;                                                \
    {                                                                         \
      const int row = t >> 2, sl = t & 3;                                     \
      const int gcol = kb + ((sl ^ ((row >> 1) & 3)) << 3);                   \
      dma16(Ab + (size_t)row * N_ + gcol, &lds[buf][t * 8]);                  \
    }                                                                         \
    _Pragma("unroll") for (int r = 0; r < 2; ++r) {                           \
      const int c = r * 512 + t;                                              \
      const int row = c >> 2, sl = c & 3;                                     \
      const int gcol = kb + ((sl ^ ((row >> 1) & 3)) << 3);                   \
      dma16(Bb + (size_t)row * N_ + gcol, &lds[buf][4096 + c * 8]);           \
    }                                                                         \
  }

  STAGE2(0, 0);
  STAGE2(1, 1);
  asm volatile("s_waitcnt vmcnt(%0)" ::"i"(K2_LOADS) : "memory");
  __builtin_amdgcn_s_barrier();
  const int NT = N_ / 32;  // 64
  for (int kt_ = 0; kt_ < NT; ++kt_) {
    const int b = kt_ % 3;
    const bool pf = (kt_ + 2 < NT);
    if (pf) STAGE2((kt_ + 2) % 3, kt_ + 2);
    const u16* LA = &lds[b][0];
    const u16* LB = &lds[b][4096];
    short8 af[4], bfv[4];
#pragma unroll
    for (int i = 0; i < 4; ++i) {
      const int row = wm * 64 + i * 16 + fr;
      af[i] = *(const short8*)&LA[row * 32 + ((g ^ ((row >> 1) & 3)) << 3)];
    }
#pragma unroll
    for (int j = 0; j < 4; ++j) {
      const int row = wn * 64 + j * 16 + fr;
      bfv[j] = *(const short8*)&LB[row * 32 + ((g ^ ((row >> 1) & 3)) << 3)];
    }
#pragma unroll
    for (int i = 0; i < 4; ++i)
#pragma unroll
      for (int j = 0; j < 4; ++j)
        acc[i][j] = __builtin_amdgcn_mfma_f32_16x16x32_bf16(af[i], bfv[j], acc[i][j], 0, 0, 0);
    if (pf)
      asm volatile("s_waitcnt vmcnt(%0) lgkmcnt(0)" ::"i"(K2_LOADS) : "memory");
    else
      asm volatile("s_waitcnt vmcnt(0) lgkmcnt(0)" ::: "memory");
    __builtin_amdgcn_s_barrier();
  }
#undef STAGE2

  const int cr = lane >> 4, cc = lane & 15;
  const size_t ob = (size_t)bz * H_ * N_;
#pragma unroll
  for (int i = 0; i < 4; ++i) {
    const int hh = h0 + wm * 64 + i * 16 + cr * 4;
#pragma unroll
    for (int j = 0; j < 4; ++j) {
      const int nn = n0 + wn * 64 + j * 16 + cc;
#pragma unroll
      for (int r = 0; r < 4; ++r)
        out[ob + (size_t)(hh + r) * N_ + nn] = acc[i][j][r];
    }
  }
}

// ---------------------------------------------------------------------------
extern "C" void kernel_launch(void* const* d_in, const int* in_sizes, int n_in,
                              void* d_out, int out_size, void* d_ws, size_t ws_size,
                              hipStream_t stream) {
  const float* q = (const float*)d_in[0];
  const float* k = (const float*)d_in[1];
  const float* v = (const float*)d_in[2];
  const float* pe = (const float*)d_in[3];
  float* out = (float*)d_out;
  char* ws = (char*)d_ws;
  // ws layout: qT (48 MiB) | keffT (48 MiB) | S/P (128 MiB)  => 224 MiB total
  // vB (48 MiB) REUSES the qT region: qT is dead after k1, stream is serial.
  u16* qT = (u16*)ws;
  u16* keffT = (u16*)(ws + 50331648);
  u16* S = (u16*)(ws + 100663296);
  u16* vB = (u16*)ws;

  hipLaunchKernelGGL(kt_transpose, dim3(32, 12, 32), dim3(256), 0, stream, q, k, pe, qT, keffT);
  hipLaunchKernelGGL(k1_qk_gemm, dim3(8, 8, 16), dim3(512), 0, stream, qT, keffT, S);
  // qT now dead -> overwrite with bf16 v
  hipLaunchKernelGGL(kv_convert, dim3(12288), dim3(256), 0, stream, v, vB);
  hipLaunchKernelGGL(k1b_softmax, dim3(8192), dim3(256), 0, stream, S);
  hipLaunchKernelGGL(k2_pv_gemm, dim3(8, 6, 16), dim3(512), 0, stream, vB, S, out);
}